// Round 2
// baseline (172.867 us; speedup 1.0000x reference)
//
#include <hip/hip_runtime.h>

typedef float f4 __attribute__((ext_vector_type(4)));

#define B_ 32
#define T_ 1024
#define J_ 128
#define D_ 256

// ---------------- K1: Bq[b,j,d] = w3[d]*q[b,j,d] + w1[d];  sq[b,j] = q[b,j,:].w2 ----------------
__global__ __launch_bounds__(256) void k_prep(const float* __restrict__ q, const float* __restrict__ w,
                                              float* __restrict__ Bq, float* __restrict__ sq) {
    int bj = blockIdx.x;          // b*J + j
    int d = threadIdx.x;          // 0..255
    float qv = q[bj * D_ + d];
    float w1 = w[d], w2 = w[D_ + d], w3 = w[2 * D_ + d];
    Bq[bj * D_ + d] = w3 * qv + w1;
    float p = qv * w2;
#pragma unroll
    for (int m = 32; m >= 1; m >>= 1) p += __shfl_xor(p, m);
    __shared__ float red[4];
    if ((d & 63) == 0) red[d >> 6] = p;
    __syncthreads();
    if (d == 0) sq[bj] = red[0] + red[1] + red[2] + red[3];
}

// ---------------- K2: per (b, 64-t tile): S GEMM -> softmax -> c2q GEMM -> write out q2,q3; write M ----------------
__global__ __launch_bounds__(256) void k_main(const float* __restrict__ ctx, const float* __restrict__ query,
                                              const float* __restrict__ Bq, const float* __restrict__ sq,
                                              float* __restrict__ M, float* __restrict__ out) {
    __shared__ float lds[12288];              // 48 KB
    float* As = lds;                          // [64][32]  row-major (phase A)
    float* Bs = lds + 2048;                   // [32][128] k-major   (phase A)
    float* aS = lds;                          // [64][128]           (phase B)
    float* Qs = lds + 8192;                   // [16][256]           (phase B)

    int b  = blockIdx.x >> 4;
    int t0 = (blockIdx.x & 15) << 6;
    int tid = threadIdx.x;
    int tx = tid & 15, ty = tid >> 4;

    const float* ctxB = ctx + (b * T_ + t0) * D_;
    const float* BqB  = Bq + b * J_ * D_;

    f4 acc[4][2];                             // S tile: rows ty*4+i, cols tx*4 + s*64 + u
#pragma unroll
    for (int i = 0; i < 4; i++)
#pragma unroll
        for (int s = 0; s < 2; s++) acc[i][s] = (f4){0.f, 0.f, 0.f, 0.f};

    for (int kt = 0; kt < 8; ++kt) {
        // A tile 64x32 (2 f4 per thread, contiguous stores)
#pragma unroll
        for (int it = 0; it < 2; ++it) {
            int l = tid + it * 256;
            int r = l >> 3, c4 = l & 7;
            *(f4*)&As[r * 32 + c4 * 4] = *(const f4*)&ctxB[r * D_ + kt * 32 + c4 * 4];
        }
        // B tile 128x32 -> transposed to Bs[k][j]
#pragma unroll
        for (int it = 0; it < 4; ++it) {
            int l = tid + it * 256;
            int j = l >> 3, c4 = l & 7;
            f4 v = *(const f4*)&BqB[j * D_ + kt * 32 + c4 * 4];
#pragma unroll
            for (int u = 0; u < 4; u++) Bs[(c4 * 4 + u) * 128 + j] = v[u];
        }
        __syncthreads();
#pragma unroll
        for (int k4 = 0; k4 < 8; k4++) {
            f4 av[4];
#pragma unroll
            for (int i = 0; i < 4; i++) av[i] = *(f4*)&As[(ty * 4 + i) * 32 + k4 * 4];
#pragma unroll
            for (int kk = 0; kk < 4; kk++) {
#pragma unroll
                for (int s = 0; s < 2; s++) {
                    f4 bv = *(f4*)&Bs[(k4 * 4 + kk) * 128 + tx * 4 + s * 64];
#pragma unroll
                    for (int i = 0; i < 4; i++) acc[i][s] += av[i][kk] * bv;
                }
            }
        }
        __syncthreads();
    }

    // bias + row softmax (rows owned across the 16 tx-lanes of each ty group)
    f4 sqv0 = *(const f4*)&sq[b * J_ + tx * 4];
    f4 sqv1 = *(const f4*)&sq[b * J_ + tx * 4 + 64];
    float mrow[4];
#pragma unroll
    for (int i = 0; i < 4; i++) {
        acc[i][0] += sqv0;
        acc[i][1] += sqv1;
        float m = acc[i][0][0];
#pragma unroll
        for (int s = 0; s < 2; s++)
#pragma unroll
            for (int u = 0; u < 4; u++) m = fmaxf(m, acc[i][s][u]);
#pragma unroll
        for (int msk = 8; msk >= 1; msk >>= 1) m = fmaxf(m, __shfl_xor(m, msk));
        float sm = 0.f;
#pragma unroll
        for (int s = 0; s < 2; s++)
#pragma unroll
            for (int u = 0; u < 4; u++) {
                float e = __expf(acc[i][s][u] - m);
                acc[i][s][u] = e;
                sm += e;
            }
#pragma unroll
        for (int msk = 8; msk >= 1; msk >>= 1) sm += __shfl_xor(sm, msk);
        float inv = 1.0f / sm;
        acc[i][0] *= inv;
        acc[i][1] *= inv;
        mrow[i] = m;
    }
    if (tx == 0) {
#pragma unroll
        for (int i = 0; i < 4; i++) M[b * T_ + t0 + ty * 4 + i] = mrow[i];
    }

    // stash a into LDS (phase-A tiles fully consumed; last __syncthreads() above covers all threads)
#pragma unroll
    for (int i = 0; i < 4; i++)
#pragma unroll
        for (int s = 0; s < 2; s++)
            *(f4*)&aS[(ty * 4 + i) * 128 + tx * 4 + s * 64] = acc[i][s];

    // phase B: c2q tile 64x256, cols tx*4 + s*64 + u
    f4 acc2[4][4];
#pragma unroll
    for (int i = 0; i < 4; i++)
#pragma unroll
        for (int s = 0; s < 4; s++) acc2[i][s] = (f4){0.f, 0.f, 0.f, 0.f};

    for (int jc = 0; jc < 8; ++jc) {
        __syncthreads();   // aS writes visible (jc=0); protect Qs from previous iter's readers (jc>0)
#pragma unroll
        for (int it = 0; it < 4; ++it) {
            int l = tid + it * 256;
            int jj = l >> 6, d4 = l & 63;
            *(f4*)&Qs[jj * 256 + d4 * 4] = *(const f4*)&query[(b * J_ + jc * 16 + jj) * D_ + d4 * 4];
        }
        __syncthreads();
#pragma unroll
        for (int j4 = 0; j4 < 4; j4++) {
            f4 a4[4];
#pragma unroll
            for (int i = 0; i < 4; i++) a4[i] = *(f4*)&aS[(ty * 4 + i) * 128 + jc * 16 + j4 * 4];
#pragma unroll
            for (int jj = 0; jj < 4; jj++) {
#pragma unroll
                for (int s = 0; s < 4; s++) {
                    f4 qv = *(f4*)&Qs[(j4 * 4 + jj) * 256 + tx * 4 + s * 64];
#pragma unroll
                    for (int i = 0; i < 4; i++) acc2[i][s] += a4[i][jj] * qv;
                }
            }
        }
    }

    // epilogue: write quarters 2 (c2q) and 3 (ctx*c2q)
#pragma unroll
    for (int i = 0; i < 4; i++) {
        int r = t0 + ty * 4 + i;
        const float* crow = ctx + (b * T_ + r) * D_;
        float* orow = out + (b * T_ + r) * 1024;
#pragma unroll
        for (int s = 0; s < 4; s++) {
            int c = tx * 4 + s * 64;
            f4 cv = acc2[i][s];
            f4 xv = *(const f4*)&crow[c];
            *(f4*)&orow[256 + c] = cv;
            *(f4*)&orow[512 + c] = xv * cv;
        }
    }
}

// ---------------- K3: b = softmax(M[b,:]) over T; q2c[b,d] = sum_t b_t * ctx[b,t,d] ----------------
__global__ __launch_bounds__(256) void k_q2c(const float* __restrict__ ctx, const float* __restrict__ M,
                                             float* __restrict__ q2c) {
    int b = blockIdx.x >> 2;
    int dc = blockIdx.x & 3;
    int tid = threadIdx.x;
    const float* Mb = M + b * T_;

    float mx = -1e30f;
    for (int i = tid; i < T_; i += 256) mx = fmaxf(mx, Mb[i]);
#pragma unroll
    for (int m = 32; m >= 1; m >>= 1) mx = fmaxf(mx, __shfl_xor(mx, m));
    __shared__ float rA[4], rB[4];
    if ((tid & 63) == 0) rA[tid >> 6] = mx;
    __syncthreads();
    mx = fmaxf(fmaxf(rA[0], rA[1]), fmaxf(rA[2], rA[3]));

    float sm = 0.f;
    for (int i = tid; i < T_; i += 256) sm += __expf(Mb[i] - mx);
#pragma unroll
    for (int m = 32; m >= 1; m >>= 1) sm += __shfl_xor(sm, m);
    if ((tid & 63) == 0) rB[tid >> 6] = sm;
    __syncthreads();
    sm = rB[0] + rB[1] + rB[2] + rB[3];

    int g = tid >> 6, dl = tid & 63;
    int d = dc * 64 + dl;
    float acc = 0.f;
    for (int t = g; t < T_; t += 4)
        acc += __expf(Mb[t] - mx) * ctx[(b * T_ + t) * D_ + d];
    __shared__ float red[4][64];
    red[g][dl] = acc;
    __syncthreads();
    if (g == 0) q2c[b * D_ + d] = (red[0][dl] + red[1][dl] + red[2][dl] + red[3][dl]) / sm;
}

// ---------------- K4: quarters 1 (ctx) and 4 (ctx*q2c) ----------------
__global__ __launch_bounds__(256) void k_out14(const float* __restrict__ ctx, const float* __restrict__ q2c,
                                               float* __restrict__ out) {
    int idx = blockIdx.x * 256 + threadIdx.x;   // f4 index
    int e = idx * 4;
    int b = e >> 18;            // T*D = 2^18
    int t = (e >> 8) & 1023;
    int d = e & 255;
    f4 cv = *(const f4*)&ctx[e];
    f4 qv = *(const f4*)&q2c[b * D_ + d];
    int ob = (b * T_ + t) * 1024 + d;
    *(f4*)&out[ob] = cv;
    *(f4*)&out[ob + 768] = cv * qv;
}

extern "C" void kernel_launch(void* const* d_in, const int* in_sizes, int n_in,
                              void* d_out, int out_size, void* d_ws, size_t ws_size,
                              hipStream_t stream) {
    const float* ctx   = (const float*)d_in[0];
    const float* query = (const float*)d_in[1];
    const float* w     = (const float*)d_in[2];
    float* out = (float*)d_out;
    float* ws  = (float*)d_ws;

    float* Bq  = ws;                  // 32*128*256 = 1048576 floats
    float* sq  = ws + 1048576;        // 4096
    float* M   = ws + 1052672;        // 32768
    float* q2c = ws + 1085440;        // 8192

    k_prep<<<B_ * J_, 256, 0, stream>>>(query, w, Bq, sq);
    k_main<<<B_ * (T_ / 64), 256, 0, stream>>>(ctx, query, Bq, sq, M, out);
    k_q2c<<<B_ * 4, 256, 0, stream>>>(ctx, M, q2c);
    k_out14<<<(B_ * T_ * D_ / 4) / 256, 256, 0, stream>>>(ctx, q2c, out);
}

// Round 3
// 126.429 us; speedup vs baseline: 1.3673x; 1.3673x over previous
//
#include <hip/hip_runtime.h>

typedef float f4 __attribute__((ext_vector_type(4)));
typedef short s8v __attribute__((ext_vector_type(8)));   // 8 bf16 in 4 VGPRs

#define B_ 32
#define T_ 1024
#define J_ 128
#define D_ 256

__device__ inline unsigned short f2bf(float x) {
    unsigned int u = __float_as_uint(x);
    u += 0x7fffu + ((u >> 16) & 1u);      // RNE
    return (unsigned short)(u >> 16);
}
__device__ inline float bf2f(unsigned short h) {
    return __uint_as_float(((unsigned int)h) << 16);
}

// ---------------- K1: Bqh[b,j,d] = bf16(w3*q+w1); sq[b,j] = q[b,j,:].w2 ----------------
__global__ __launch_bounds__(256) void k_prep(const float* __restrict__ q, const float* __restrict__ w,
                                              unsigned short* __restrict__ Bqh, float* __restrict__ sq) {
    int bj = blockIdx.x;
    int d = threadIdx.x;
    float qv = q[bj * D_ + d];
    float w1 = w[d], w2 = w[D_ + d], w3 = w[2 * D_ + d];
    Bqh[bj * D_ + d] = f2bf(w3 * qv + w1);
    float p = qv * w2;
#pragma unroll
    for (int m = 32; m >= 1; m >>= 1) p += __shfl_xor(p, m);
    __shared__ float red[4];
    if ((d & 63) == 0) red[d >> 6] = p;
    __syncthreads();
    if (d == 0) sq[bj] = red[0] + red[1] + red[2] + red[3];
}

// ---------------- K1b: qT_hi/lo[b,d,j] = transpose + hi/lo bf16 split of query ----------------
__global__ __launch_bounds__(256) void k_tq(const float* __restrict__ q,
                                            unsigned short* __restrict__ qTh, unsigned short* __restrict__ qTl) {
    __shared__ float t_[64][65];
    int b = blockIdx.x >> 3, jt = (blockIdx.x >> 2) & 1, dt = blockIdx.x & 3;
    const float* qb = q + (b * J_ + jt * 64) * D_ + dt * 64;
#pragma unroll
    for (int i = 0; i < 16; i++) {
        int lin = threadIdx.x + 256 * i;
        int jj = lin >> 6, dd = lin & 63;
        t_[jj][dd] = qb[jj * D_ + dd];
    }
    __syncthreads();
#pragma unroll
    for (int i = 0; i < 16; i++) {
        int lin = threadIdx.x + 256 * i;
        int dd = lin >> 6, jj = lin & 63;
        float v = t_[jj][dd];
        unsigned short h = f2bf(v);
        unsigned short lo = f2bf(v - bf2f(h));
        int o = (b * D_ + dt * 64 + dd) * J_ + jt * 64 + jj;
        qTh[o] = h;
        qTl[o] = lo;
    }
}

// ---------------- K2: MFMA S-GEMM -> softmax -> MFMA PV -> write q2,q3; write M ----------------
__global__ __launch_bounds__(256) void k_main(const float* __restrict__ ctx,
                                              const unsigned short* __restrict__ Bqh,
                                              const unsigned short* __restrict__ qTh,
                                              const unsigned short* __restrict__ qTl,
                                              const float* __restrict__ sq,
                                              float* __restrict__ M, float* __restrict__ out) {
    __shared__ __align__(16) unsigned short Pl[64 * 128];   // 16 KB, wave-local rows, XOR-swizzled chunks
    int b = blockIdx.x >> 4;
    int t0 = (blockIdx.x & 15) << 6;
    int tid = threadIdx.x;
    int w = tid >> 6, l = tid & 63, lr = l & 15, lq = l >> 4;
    int tw = t0 + w * 16;                 // wave's 16 rows

    // ---- phase A: S[tw..tw+15][0..127] = ctx . Bq^T ----
    f4 acc[8];
#pragma unroll
    for (int nf = 0; nf < 8; nf++) acc[nf] = (f4){0.f, 0.f, 0.f, 0.f};

    const float* ctxA = ctx + (b * T_ + tw + lr) * D_;
    const unsigned short* BqB = Bqh + (b * J_) * D_;
#pragma unroll
    for (int k = 0; k < 8; ++k) {
        int d0 = k * 32 + lq * 8;
        f4 a0 = *(const f4*)(ctxA + d0);
        f4 a1 = *(const f4*)(ctxA + d0 + 4);
        union { unsigned short u[8]; s8v v; } af;
#pragma unroll
        for (int e = 0; e < 4; e++) { af.u[e] = f2bf(a0[e]); af.u[e + 4] = f2bf(a1[e]); }
#pragma unroll
        for (int nf = 0; nf < 8; nf++) {
            s8v bv = *(const s8v*)(BqB + (nf * 16 + lr) * D_ + d0);
            acc[nf] = __builtin_amdgcn_mfma_f32_16x16x32_bf16(af.v, bv, acc[nf], 0, 0, 0);
        }
    }

    // ---- bias + row softmax; P -> LDS (bf16, chunk-swizzled) ----
    float sqv[8];
#pragma unroll
    for (int nf = 0; nf < 8; nf++) sqv[nf] = sq[b * J_ + nf * 16 + lr];
    int rowbase = w * 16 + lq * 4;
#pragma unroll
    for (int r = 0; r < 4; r++) {
        float ev[8];
        float mr = -1e30f;
#pragma unroll
        for (int nf = 0; nf < 8; nf++) { ev[nf] = acc[nf][r] + sqv[nf]; mr = fmaxf(mr, ev[nf]); }
#pragma unroll
        for (int msk = 8; msk >= 1; msk >>= 1) mr = fmaxf(mr, __shfl_xor(mr, msk));
        float s = 0.f;
#pragma unroll
        for (int nf = 0; nf < 8; nf++) { ev[nf] = __expf(ev[nf] - mr); s += ev[nf]; }
#pragma unroll
        for (int msk = 8; msk >= 1; msk >>= 1) s += __shfl_xor(s, msk);
        float inv = 1.0f / s;
        int row = rowbase + r;
        int sw = row & 7;
#pragma unroll
        for (int nf = 0; nf < 8; nf++) {
            int c = 2 * nf + (lr >> 3);                      // 16B chunk within row
            int byte_off = row * 256 + ((c ^ sw) << 4) + ((lr & 7) << 1);
            *(unsigned short*)((char*)Pl + byte_off) = f2bf(ev[nf] * inv);
        }
        if (lr == 0) M[b * T_ + t0 + row] = mr;
    }

    // ---- phase B: c2q = P . q  (q split hi+lo) ----
    f4 acc2[16];
#pragma unroll
    for (int df = 0; df < 16; df++) acc2[df] = (f4){0.f, 0.f, 0.f, 0.f};

    int prow = w * 16 + lr;
    int psw = prow & 7;
#pragma unroll
    for (int jk = 0; jk < 4; jk++) {
        int c = jk * 4 + lq;
        s8v pa = *(const s8v*)((char*)Pl + prow * 256 + ((c ^ psw) << 4));
        const unsigned short* qh = qTh + (b * D_) * J_ + jk * 32 + lq * 8;
        const unsigned short* ql = qTl + (b * D_) * J_ + jk * 32 + lq * 8;
#pragma unroll
        for (int df = 0; df < 16; df++) {
            s8v bh = *(const s8v*)(qh + (df * 16 + lr) * J_);
            acc2[df] = __builtin_amdgcn_mfma_f32_16x16x32_bf16(pa, bh, acc2[df], 0, 0, 0);
        }
#pragma unroll
        for (int df = 0; df < 16; df++) {
            s8v bl = *(const s8v*)(ql + (df * 16 + lr) * J_);
            acc2[df] = __builtin_amdgcn_mfma_f32_16x16x32_bf16(pa, bl, acc2[df], 0, 0, 0);
        }
    }

    // ---- epilogue: quarters 2 (c2q) and 3 (ctx*c2q) ----
#pragma unroll
    for (int df = 0; df < 16; df++) {
        int d = df * 16 + lr;
#pragma unroll
        for (int r = 0; r < 4; r++) {
            int t = t0 + rowbase + r;
            int o = b * T_ + t;
            float val = acc2[df][r];
            float cx = ctx[o * D_ + d];
            out[o * 1024 + 256 + d] = val;
            out[o * 1024 + 512 + d] = cx * val;
        }
    }
}

// ---------------- K3: softmax(M) over T; q2c[b,d] = sum_t w_t*ctx[b,t,d] ----------------
__global__ __launch_bounds__(256) void k_q2c(const float* __restrict__ ctx, const float* __restrict__ M,
                                             float* __restrict__ q2c) {
    int b = blockIdx.x >> 4, dc = blockIdx.x & 15;
    int tid = threadIdx.x;
    const float* Mb = M + b * T_;

    float mx = -1e30f;
    for (int i = tid; i < T_; i += 256) mx = fmaxf(mx, Mb[i]);
#pragma unroll
    for (int m = 32; m >= 1; m >>= 1) mx = fmaxf(mx, __shfl_xor(mx, m));
    __shared__ float rA[4], rB[4];
    if ((tid & 63) == 0) rA[tid >> 6] = mx;
    __syncthreads();
    mx = fmaxf(fmaxf(rA[0], rA[1]), fmaxf(rA[2], rA[3]));

    float sm = 0.f;
    for (int i = tid; i < T_; i += 256) sm += __expf(Mb[i] - mx);
#pragma unroll
    for (int m = 32; m >= 1; m >>= 1) sm += __shfl_xor(sm, m);
    if ((tid & 63) == 0) rB[tid >> 6] = sm;
    __syncthreads();
    sm = rB[0] + rB[1] + rB[2] + rB[3];

    int dl = tid & 15, g = tid >> 4;
    int d = dc * 16 + dl;
    float acc = 0.f;
    for (int t = g; t < T_; t += 16)
        acc += __expf(Mb[t] - mx) * ctx[(b * T_ + t) * D_ + d];
    __shared__ float red[16][17];
    red[g][dl] = acc;
    __syncthreads();
    if (g == 0) {
        float s = 0.f;
#pragma unroll
        for (int k2 = 0; k2 < 16; k2++) s += red[k2][dl];
        q2c[b * D_ + d] = s / sm;
    }
}

// ---------------- K4: quarters 1 (ctx) and 4 (ctx*q2c) ----------------
__global__ __launch_bounds__(256) void k_out14(const float* __restrict__ ctx, const float* __restrict__ q2c,
                                               float* __restrict__ out) {
    int idx = blockIdx.x * 256 + threadIdx.x;   // f4 index
    int e = idx * 4;
    int b = e >> 18;            // T*D = 2^18
    int t = (e >> 8) & 1023;
    int d = e & 255;
    f4 cv = *(const f4*)&ctx[e];
    f4 qv = *(const f4*)&q2c[b * D_ + d];
    int ob = (b * T_ + t) * 1024 + d;
    *(f4*)&out[ob] = cv;
    *(f4*)&out[ob + 768] = cv * qv;
}

extern "C" void kernel_launch(void* const* d_in, const int* in_sizes, int n_in,
                              void* d_out, int out_size, void* d_ws, size_t ws_size,
                              hipStream_t stream) {
    const float* ctx   = (const float*)d_in[0];
    const float* query = (const float*)d_in[1];
    const float* w     = (const float*)d_in[2];
    float* out = (float*)d_out;

    unsigned short* Bqh = (unsigned short*)d_ws;        // 1M u16 = 2 MB
    unsigned short* qTh = Bqh + B_ * J_ * D_;           // 2 MB
    unsigned short* qTl = qTh + B_ * J_ * D_;           // 2 MB
    float* fws = (float*)(qTl + B_ * J_ * D_);
    float* sq  = fws;                                   // 4096
    float* M   = fws + 4096;                            // 32768
    float* q2c = fws + 4096 + 32768;                    // 8192

    k_prep<<<B_ * J_, 256, 0, stream>>>(query, w, Bqh, sq);
    k_tq<<<B_ * 2 * 4, 256, 0, stream>>>(query, qTh, qTl);
    k_main<<<B_ * (T_ / 64), 256, 0, stream>>>(ctx, Bqh, qTh, qTl, sq, M, out);
    k_q2c<<<B_ * 16, 256, 0, stream>>>(ctx, M, q2c);
    k_out14<<<(B_ * T_ * D_ / 4) / 256, 256, 0, stream>>>(ctx, q2c, out);
}

// Round 4
// 93.391 us; speedup vs baseline: 1.8510x; 1.3538x over previous
//
#include <hip/hip_runtime.h>

typedef float f4 __attribute__((ext_vector_type(4)));
typedef short s8v __attribute__((ext_vector_type(8)));        // 8 bf16
typedef unsigned int u4v __attribute__((ext_vector_type(4))); // 16 B

#define B_ 32
#define T_ 1024
#define J_ 128
#define D_ 256

__device__ inline unsigned short f2bf(float x) {
    unsigned int u = __float_as_uint(x);
    u += 0x7fffu + ((u >> 16) & 1u);      // RNE
    return (unsigned short)(u >> 16);
}
__device__ inline float bf2f(unsigned short h) {
    return __uint_as_float(((unsigned int)h) << 16);
}

// ---------------- K1: Bqh[b,j,d] = bf16(w3*q+w1); sq[b,j] = q[b,j,:].w2 ----------------
__global__ __launch_bounds__(256) void k_prep(const float* __restrict__ q, const float* __restrict__ w,
                                              unsigned short* __restrict__ Bqh, float* __restrict__ sq) {
    int bj = blockIdx.x;
    int d = threadIdx.x;
    float qv = q[bj * D_ + d];
    float w1 = w[d], w2 = w[D_ + d], w3 = w[2 * D_ + d];
    Bqh[bj * D_ + d] = f2bf(w3 * qv + w1);
    float p = qv * w2;
#pragma unroll
    for (int m = 32; m >= 1; m >>= 1) p += __shfl_xor(p, m);
    __shared__ float red[4];
    if ((d & 63) == 0) red[d >> 6] = p;
    __syncthreads();
    if (d == 0) sq[bj] = red[0] + red[1] + red[2] + red[3];
}

// ---------------- K1b: qT_hi/lo[b,d,j] = transpose + hi/lo bf16 split of query ----------------
__global__ __launch_bounds__(256) void k_tq(const float* __restrict__ q,
                                            unsigned short* __restrict__ qTh, unsigned short* __restrict__ qTl) {
    __shared__ float t_[64][65];
    int b = blockIdx.x >> 3, jt = (blockIdx.x >> 2) & 1, dt = blockIdx.x & 3;
    const float* qb = q + (b * J_ + jt * 64) * D_ + dt * 64;
#pragma unroll
    for (int i = 0; i < 16; i++) {
        int lin = threadIdx.x + 256 * i;
        int jj = lin >> 6, dd = lin & 63;
        t_[jj][dd] = qb[jj * D_ + dd];
    }
    __syncthreads();
#pragma unroll
    for (int i = 0; i < 16; i++) {
        int lin = threadIdx.x + 256 * i;
        int dd = lin >> 6, jj = lin & 63;
        float v = t_[jj][dd];
        unsigned short h = f2bf(v);
        unsigned short lo = f2bf(v - bf2f(h));
        int o = (b * D_ + dt * 64 + dd) * J_ + jt * 64 + jj;
        qTh[o] = h;
        qTl[o] = lo;
    }
}

// ---------------- K2: LDS-staged MFMA S-GEMM -> softmax -> MFMA PV -> write q2,q3; write M ----------------
__global__ __launch_bounds__(256) void k_main(const float* __restrict__ ctx,
                                              const unsigned short* __restrict__ Bqh,
                                              const unsigned short* __restrict__ qTh,
                                              const unsigned short* __restrict__ qTl,
                                              const float* __restrict__ sq,
                                              float* __restrict__ M, float* __restrict__ out) {
    __shared__ __align__(16) unsigned short lds[24576];   // 48 KB
    unsigned short* Bs = lds;            // [64][256] bf16 swizzled (32 KB); reused as Qs in phase B
    unsigned short* Ps = lds + 16384;    // [64][128] bf16 swizzled (16 KB)

    int b  = blockIdx.x >> 4;
    int t0 = (blockIdx.x & 15) << 6;
    int tid = threadIdx.x;
    int w = tid >> 6, l = tid & 63, lr = l & 15, lq = l >> 4;
    int tw = t0 + w * 16;

    const unsigned short* BqB  = Bqh + b * J_ * D_;
    const unsigned short* qThB = qTh + b * D_ * J_;
    const unsigned short* qTlB = qTl + b * D_ * J_;

    // ---- stage Bq half 0 (j=0..63) ----
#pragma unroll
    for (int i = 0; i < 8; i++) {
        int g = tid + (i << 8);                 // 0..2047 chunk id
        int jr = g >> 5, c = g & 31;
        u4v v = *(const u4v*)(BqB + jr * D_ + (c << 3));
        *(u4v*)((char*)Bs + jr * 512 + ((c ^ (jr & 7)) << 4)) = v;
    }

    // ---- ctx rows -> bf16 A-frags in registers (reused for both halves) ----
    const float* ctxA = ctx + (b * T_ + tw + lr) * D_;
    s8v af[8];
#pragma unroll
    for (int k = 0; k < 8; k++) {
        f4 c0 = *(const f4*)(ctxA + k * 32 + lq * 8);
        f4 c1 = *(const f4*)(ctxA + k * 32 + lq * 8 + 4);
        union { unsigned short u[8]; s8v v; } t;
#pragma unroll
        for (int e = 0; e < 4; e++) { t.u[e] = f2bf(c0[e]); t.u[e + 4] = f2bf(c1[e]); }
        af[k] = t.v;
    }

    f4 acc[8];
#pragma unroll
    for (int nf = 0; nf < 8; nf++) acc[nf] = (f4){0.f, 0.f, 0.f, 0.f};

    __syncthreads();
    // ---- phase A half 0: acc[0..3] ----
#pragma unroll
    for (int k = 0; k < 8; k++) {
#pragma unroll
        for (int nf = 0; nf < 4; nf++) {
            int jr = nf * 16 + lr;
            s8v bv = *(const s8v*)((char*)Bs + jr * 512 + ((((k << 2) | lq) ^ (jr & 7)) << 4));
            acc[nf] = __builtin_amdgcn_mfma_f32_16x16x32_bf16(af[k], bv, acc[nf], 0, 0, 0);
        }
    }
    __syncthreads();
    // ---- stage Bq half 1 (j=64..127) ----
#pragma unroll
    for (int i = 0; i < 8; i++) {
        int g = tid + (i << 8);
        int jr = g >> 5, c = g & 31;
        u4v v = *(const u4v*)(BqB + (64 + jr) * D_ + (c << 3));
        *(u4v*)((char*)Bs + jr * 512 + ((c ^ (jr & 7)) << 4)) = v;
    }
    __syncthreads();
    // ---- phase A half 1: acc[4..7] ----
#pragma unroll
    for (int k = 0; k < 8; k++) {
#pragma unroll
        for (int nf = 4; nf < 8; nf++) {
            int jr = (nf - 4) * 16 + lr;
            s8v bv = *(const s8v*)((char*)Bs + jr * 512 + ((((k << 2) | lq) ^ (jr & 7)) << 4));
            acc[nf] = __builtin_amdgcn_mfma_f32_16x16x32_bf16(af[k], bv, acc[nf], 0, 0, 0);
        }
    }

    // ---- bias + row softmax; P -> LDS (bf16, swizzled) ----
    float sqv[8];
#pragma unroll
    for (int nf = 0; nf < 8; nf++) sqv[nf] = sq[b * J_ + nf * 16 + lr];
    int rowbase = w * 16 + lq * 4;
#pragma unroll
    for (int r = 0; r < 4; r++) {
        float ev[8];
        float mr = -1e30f;
#pragma unroll
        for (int nf = 0; nf < 8; nf++) { ev[nf] = acc[nf][r] + sqv[nf]; mr = fmaxf(mr, ev[nf]); }
#pragma unroll
        for (int msk = 8; msk >= 1; msk >>= 1) mr = fmaxf(mr, __shfl_xor(mr, msk));
        float s = 0.f;
#pragma unroll
        for (int nf = 0; nf < 8; nf++) { ev[nf] = __expf(ev[nf] - mr); s += ev[nf]; }
#pragma unroll
        for (int msk = 8; msk >= 1; msk >>= 1) s += __shfl_xor(s, msk);
        float inv = 1.0f / s;
        int row = rowbase + r;
        int sw = row & 7;
#pragma unroll
        for (int nf = 0; nf < 8; nf++) {
            int c = 2 * nf + (lr >> 3);
            *(unsigned short*)((char*)Ps + row * 256 + ((c ^ sw) << 4) + ((lr & 7) << 1)) = f2bf(ev[nf] * inv);
        }
        if (lr == 0) M[b * T_ + t0 + row] = mr;
    }

    __syncthreads();   // all waves done with Bs (phase A); Ps drained

    // ---- stage qT chunk 0 into Qs buf 0 (Qs aliases Bs region) ----
    u4v qreg[4];
#pragma unroll
    for (int i = 0; i < 2; i++) {
        int g = tid + (i << 8);
        int dr = g >> 4, c = g & 15;
        qreg[i]     = *(const u4v*)(qThB + dr * J_ + (c << 3));
        qreg[2 + i] = *(const u4v*)(qTlB + dr * J_ + (c << 3));
    }
#pragma unroll
    for (int i = 0; i < 2; i++) {
        int g = tid + (i << 8);
        int dr = g >> 4, c = g & 15;
        *(u4v*)((char*)Bs + dr * 256 + ((c ^ (dr & 7)) << 4)) = qreg[i];
        *(u4v*)((char*)Bs + 8192 + dr * 256 + ((c ^ (dr & 7)) << 4)) = qreg[2 + i];
    }
    __syncthreads();

    // ---- P A-frags hoisted (reused for all d-chunks and hi/lo) ----
    int prow = w * 16 + lr, psw = prow & 7;
    s8v pf[4];
#pragma unroll
    for (int jk = 0; jk < 4; jk++)
        pf[jk] = *(const s8v*)((char*)Ps + prow * 256 + ((((jk << 2) | lq) ^ psw) << 4));

    // ---- phase B: c2q = P . q, double-buffered chunks of 32 d-rows ----
    f4 acc2[16];
#pragma unroll
    for (int df = 0; df < 16; df++) acc2[df] = (f4){0.f, 0.f, 0.f, 0.f};

#pragma unroll
    for (int dfc = 0; dfc < 8; dfc++) {
        if (dfc < 7) {     // issue next-chunk global loads early (hide under MFMA)
#pragma unroll
            for (int i = 0; i < 2; i++) {
                int g = tid + (i << 8);
                int dr = g >> 4, c = g & 15;
                qreg[i]     = *(const u4v*)(qThB + ((dfc + 1) * 32 + dr) * J_ + (c << 3));
                qreg[2 + i] = *(const u4v*)(qTlB + ((dfc + 1) * 32 + dr) * J_ + (c << 3));
            }
        }
        char* qb = (char*)Bs + (dfc & 1) * 16384;
#pragma unroll
        for (int dh = 0; dh < 2; dh++) {
            int df = dfc * 2 + dh;
            int dr = dh * 16 + lr;
            int sw2 = dr & 7;
#pragma unroll
            for (int jk = 0; jk < 4; jk++) {
                s8v bh = *(const s8v*)(qb + dr * 256 + ((((jk << 2) | lq) ^ sw2) << 4));
                acc2[df] = __builtin_amdgcn_mfma_f32_16x16x32_bf16(pf[jk], bh, acc2[df], 0, 0, 0);
            }
#pragma unroll
            for (int jk = 0; jk < 4; jk++) {
                s8v bl = *(const s8v*)(qb + 8192 + dr * 256 + ((((jk << 2) | lq) ^ sw2) << 4));
                acc2[df] = __builtin_amdgcn_mfma_f32_16x16x32_bf16(pf[jk], bl, acc2[df], 0, 0, 0);
            }
        }
        __syncthreads();                    // all waves done reading buf (dfc&1)
        if (dfc < 7) {
            char* wb = (char*)Bs + ((dfc + 1) & 1) * 16384;
#pragma unroll
            for (int i = 0; i < 2; i++) {
                int g = tid + (i << 8);
                int dr = g >> 4, c = g & 15;
                *(u4v*)(wb + dr * 256 + ((c ^ (dr & 7)) << 4)) = qreg[i];
                *(u4v*)(wb + 8192 + dr * 256 + ((c ^ (dr & 7)) << 4)) = qreg[2 + i];
            }
            __syncthreads();                // staged chunk visible before next iter reads
        }
    }

    // ---- epilogue: quarters 2 (c2q) and 3 (ctx*c2q) ----
#pragma unroll
    for (int df = 0; df < 16; df++) {
        int d = df * 16 + lr;
#pragma unroll
        for (int r = 0; r < 4; r++) {
            int t = t0 + rowbase + r;
            int o = b * T_ + t;
            float val = acc2[df][r];
            float cx = ctx[o * D_ + d];
            out[o * 1024 + 256 + d] = val;
            out[o * 1024 + 512 + d] = cx * val;
        }
    }
}

// ---------------- K3: softmax(M) over T; q2c[b,d] = sum_t w_t*ctx[b,t,d] ----------------
__global__ __launch_bounds__(256) void k_q2c(const float* __restrict__ ctx, const float* __restrict__ M,
                                             float* __restrict__ q2c) {
    int b = blockIdx.x >> 4, dc = blockIdx.x & 15;
    int tid = threadIdx.x;
    const float* Mb = M + b * T_;

    float mx = -1e30f;
    for (int i = tid; i < T_; i += 256) mx = fmaxf(mx, Mb[i]);
#pragma unroll
    for (int m = 32; m >= 1; m >>= 1) mx = fmaxf(mx, __shfl_xor(mx, m));
    __shared__ float rA[4], rB[4];
    if ((tid & 63) == 0) rA[tid >> 6] = mx;
    __syncthreads();
    mx = fmaxf(fmaxf(rA[0], rA[1]), fmaxf(rA[2], rA[3]));

    float sm = 0.f;
    for (int i = tid; i < T_; i += 256) sm += __expf(Mb[i] - mx);
#pragma unroll
    for (int m = 32; m >= 1; m >>= 1) sm += __shfl_xor(sm, m);
    if ((tid & 63) == 0) rB[tid >> 6] = sm;
    __syncthreads();
    sm = rB[0] + rB[1] + rB[2] + rB[3];

    int dl = tid & 15, g = tid >> 4;
    int d = dc * 16 + dl;
    float acc = 0.f;
    for (int t = g; t < T_; t += 16)
        acc += __expf(Mb[t] - mx) * ctx[(b * T_ + t) * D_ + d];
    __shared__ float red[16][17];
    red[g][dl] = acc;
    __syncthreads();
    if (g == 0) {
        float s = 0.f;
#pragma unroll
        for (int k2 = 0; k2 < 16; k2++) s += red[k2][dl];
        q2c[b * D_ + d] = s / sm;
    }
}

// ---------------- K4: quarters 1 (ctx) and 4 (ctx*q2c) ----------------
__global__ __launch_bounds__(256) void k_out14(const float* __restrict__ ctx, const float* __restrict__ q2c,
                                               float* __restrict__ out) {
    int idx = blockIdx.x * 256 + threadIdx.x;   // f4 index
    int e = idx * 4;
    int b = e >> 18;            // T*D = 2^18
    int t = (e >> 8) & 1023;
    int d = e & 255;
    f4 cv = *(const f4*)&ctx[e];
    f4 qv = *(const f4*)&q2c[b * D_ + d];
    int ob = (b * T_ + t) * 1024 + d;
    *(f4*)&out[ob] = cv;
    *(f4*)&out[ob + 768] = cv * qv;
}

extern "C" void kernel_launch(void* const* d_in, const int* in_sizes, int n_in,
                              void* d_out, int out_size, void* d_ws, size_t ws_size,
                              hipStream_t stream) {
    const float* ctx   = (const float*)d_in[0];
    const float* query = (const float*)d_in[1];
    const float* w     = (const float*)d_in[2];
    float* out = (float*)d_out;

    unsigned short* Bqh = (unsigned short*)d_ws;        // 2 MB
    unsigned short* qTh = Bqh + B_ * J_ * D_;           // 2 MB
    unsigned short* qTl = qTh + B_ * J_ * D_;           // 2 MB
    float* fws = (float*)(qTl + B_ * J_ * D_);
    float* sq  = fws;                                   // 4096
    float* M   = fws + 4096;                            // 32768
    float* q2c = fws + 4096 + 32768;                    // 8192

    k_prep<<<B_ * J_, 256, 0, stream>>>(query, w, Bqh, sq);
    k_tq<<<B_ * 2 * 4, 256, 0, stream>>>(query, qTh, qTl);
    k_main<<<B_ * (T_ / 64), 256, 0, stream>>>(ctx, Bqh, qTh, qTl, sq, M, out);
    k_q2c<<<B_ * 16, 256, 0, stream>>>(ctx, M, q2c);
    k_out14<<<(B_ * T_ * D_ / 4) / 256, 256, 0, stream>>>(ctx, q2c, out);
}

// Round 5
// 91.640 us; speedup vs baseline: 1.8864x; 1.0191x over previous
//
#include <hip/hip_runtime.h>

typedef float f4 __attribute__((ext_vector_type(4)));
typedef short s8v __attribute__((ext_vector_type(8)));        // 8 bf16
typedef unsigned int u4v __attribute__((ext_vector_type(4))); // 16 B

#define B_ 32
#define T_ 1024
#define J_ 128
#define D_ 256

__device__ inline unsigned short f2bf(float x) {
    unsigned int u = __float_as_uint(x);
    u += 0x7fffu + ((u >> 16) & 1u);      // RNE
    return (unsigned short)(u >> 16);
}
__device__ inline float bf2f(unsigned short h) {
    return __uint_as_float(((unsigned int)h) << 16);
}

// ---------------- K1: Bqh[b,j,d] = bf16(w3*q+w1); sq[b,j] = q[b,j,:].w2 ----------------
__global__ __launch_bounds__(256) void k_prep(const float* __restrict__ q, const float* __restrict__ w,
                                              unsigned short* __restrict__ Bqh, float* __restrict__ sq) {
    int bj = blockIdx.x;
    int d = threadIdx.x;
    float qv = q[bj * D_ + d];
    float w1 = w[d], w2 = w[D_ + d], w3 = w[2 * D_ + d];
    Bqh[bj * D_ + d] = f2bf(w3 * qv + w1);
    float p = qv * w2;
#pragma unroll
    for (int m = 32; m >= 1; m >>= 1) p += __shfl_xor(p, m);
    __shared__ float red[4];
    if ((d & 63) == 0) red[d >> 6] = p;
    __syncthreads();
    if (d == 0) sq[bj] = red[0] + red[1] + red[2] + red[3];
}

// ---------------- K1b: qT_hi/lo[b,d,j] = transpose + hi/lo bf16 split of query ----------------
__global__ __launch_bounds__(256) void k_tq(const float* __restrict__ q,
                                            unsigned short* __restrict__ qTh, unsigned short* __restrict__ qTl) {
    __shared__ float t_[64][65];
    int b = blockIdx.x >> 3, jt = (blockIdx.x >> 2) & 1, dt = blockIdx.x & 3;
    const float* qb = q + (b * J_ + jt * 64) * D_ + dt * 64;
#pragma unroll
    for (int i = 0; i < 16; i++) {
        int lin = threadIdx.x + 256 * i;
        int jj = lin >> 6, dd = lin & 63;
        t_[jj][dd] = qb[jj * D_ + dd];
    }
    __syncthreads();
#pragma unroll
    for (int i = 0; i < 16; i++) {
        int lin = threadIdx.x + 256 * i;
        int dd = lin >> 6, jj = lin & 63;
        float v = t_[jj][dd];
        unsigned short h = f2bf(v);
        unsigned short lo = f2bf(v - bf2f(h));
        int o = (b * D_ + dt * 64 + dd) * J_ + jt * 64 + jj;
        qTh[o] = h;
        qTl[o] = lo;
    }
}

// ---------------- K2: LDS-staged MFMA S-GEMM -> softmax -> MFMA PV -> write q2,q3; write M ----------------
__global__ __launch_bounds__(256) void k_main(const float* __restrict__ ctx,
                                              const unsigned short* __restrict__ Bqh,
                                              const unsigned short* __restrict__ qTh,
                                              const unsigned short* __restrict__ qTl,
                                              const float* __restrict__ sq,
                                              float* __restrict__ M, float* __restrict__ out) {
    __shared__ __align__(16) unsigned short lds[24576];   // 48 KB
    unsigned short* Bs = lds;            // [64][256] bf16 swizzled (32 KB); Qs0/Qs1 (2x16KB) in phase B
    unsigned short* Ps = lds + 16384;    // [64][128] bf16 swizzled (16 KB)

    int b  = blockIdx.x >> 4;
    int t0 = (blockIdx.x & 15) << 6;
    int tid = threadIdx.x;
    int w = tid >> 6, l = tid & 63, lr = l & 15, lq = l >> 4;
    int tw = t0 + w * 16;

    const unsigned short* BqB  = Bqh + b * J_ * D_;
    const unsigned short* qThB = qTh + b * D_ * J_;
    const unsigned short* qTlB = qTl + b * D_ * J_;

    // ---- issue ALL phase-A global loads up front (T14 issue-early) ----
    u4v sreg[8];                                  // Bq half 0
#pragma unroll
    for (int i = 0; i < 8; i++) {
        int g = tid + (i << 8);
        int jr = g >> 5, c = g & 31;
        sreg[i] = *(const u4v*)(BqB + jr * D_ + (c << 3));
    }
    const float* ctxA = ctx + (b * T_ + tw + lr) * D_;
    f4 c0[8], c1[8];                              // ctx rows
#pragma unroll
    for (int k = 0; k < 8; k++) {
        c0[k] = *(const f4*)(ctxA + k * 32 + lq * 8);
        c1[k] = *(const f4*)(ctxA + k * 32 + lq * 8 + 4);
    }
    u4v breg[8];                                  // Bq half 1 (prefetch)
#pragma unroll
    for (int i = 0; i < 8; i++) {
        int g = tid + (i << 8);
        int jr = g >> 5, c = g & 31;
        breg[i] = *(const u4v*)(BqB + (64 + jr) * D_ + (c << 3));
    }

    // ---- write half 0 to LDS (waits only on sreg) ----
#pragma unroll
    for (int i = 0; i < 8; i++) {
        int g = tid + (i << 8);
        int jr = g >> 5, c = g & 31;
        *(u4v*)((char*)Bs + jr * 512 + ((c ^ (jr & 7)) << 4)) = sreg[i];
    }

    // ---- convert ctx -> bf16 A-frags ----
    s8v af[8];
#pragma unroll
    for (int k = 0; k < 8; k++) {
        union { unsigned short u[8]; s8v v; } t;
#pragma unroll
        for (int e = 0; e < 4; e++) { t.u[e] = f2bf(c0[k][e]); t.u[e + 4] = f2bf(c1[k][e]); }
        af[k] = t.v;
    }

    f4 acc[8];
#pragma unroll
    for (int nf = 0; nf < 8; nf++) acc[nf] = (f4){0.f, 0.f, 0.f, 0.f};

    __syncthreads();                              // #1: half 0 visible
#pragma unroll
    for (int k = 0; k < 8; k++) {
#pragma unroll
        for (int nf = 0; nf < 4; nf++) {
            int jr = nf * 16 + lr;
            s8v bv = *(const s8v*)((char*)Bs + jr * 512 + ((((k << 2) | lq) ^ (jr & 7)) << 4));
            acc[nf] = __builtin_amdgcn_mfma_f32_16x16x32_bf16(af[k], bv, acc[nf], 0, 0, 0);
        }
    }
    __syncthreads();                              // #2: all waves done reading half 0
#pragma unroll
    for (int i = 0; i < 8; i++) {
        int g = tid + (i << 8);
        int jr = g >> 5, c = g & 31;
        *(u4v*)((char*)Bs + jr * 512 + ((c ^ (jr & 7)) << 4)) = breg[i];
    }
    // issue qT stage-0 loads (hi, d=0..63) while half-1 MFMAs run
    u4v qreg[4];
#pragma unroll
    for (int i = 0; i < 4; i++) {
        int g = tid + (i << 8);
        int dr = g >> 4, cq = g & 15;
        qreg[i] = *(const u4v*)(qThB + dr * J_ + (cq << 3));
    }
    __syncthreads();                              // #3: half 1 visible
#pragma unroll
    for (int k = 0; k < 8; k++) {
#pragma unroll
        for (int nf = 4; nf < 8; nf++) {
            int jr = (nf - 4) * 16 + lr;
            s8v bv = *(const s8v*)((char*)Bs + jr * 512 + ((((k << 2) | lq) ^ (jr & 7)) << 4));
            acc[nf] = __builtin_amdgcn_mfma_f32_16x16x32_bf16(af[k], bv, acc[nf], 0, 0, 0);
        }
    }

    // ---- bias + row softmax; P -> Ps (wave-local rows, no barrier needed) ----
    float sqv[8];
#pragma unroll
    for (int nf = 0; nf < 8; nf++) sqv[nf] = sq[b * J_ + nf * 16 + lr];
    int rowbase = w * 16 + lq * 4;
#pragma unroll
    for (int r = 0; r < 4; r++) {
        float ev[8];
        float mr = -1e30f;
#pragma unroll
        for (int nf = 0; nf < 8; nf++) { ev[nf] = acc[nf][r] + sqv[nf]; mr = fmaxf(mr, ev[nf]); }
#pragma unroll
        for (int msk = 8; msk >= 1; msk >>= 1) mr = fmaxf(mr, __shfl_xor(mr, msk));
        float s = 0.f;
#pragma unroll
        for (int nf = 0; nf < 8; nf++) { ev[nf] = __expf(ev[nf] - mr); s += ev[nf]; }
#pragma unroll
        for (int msk = 8; msk >= 1; msk >>= 1) s += __shfl_xor(s, msk);
        float inv = 1.0f / s;
        int row = rowbase + r;
        int sw = row & 7;
#pragma unroll
        for (int nf = 0; nf < 8; nf++) {
            int c = 2 * nf + (lr >> 3);
            *(unsigned short*)((char*)Ps + row * 256 + ((c ^ sw) << 4) + ((lr & 7) << 1)) = f2bf(ev[nf] * inv);
        }
        if (lr == 0) M[b * T_ + t0 + row] = mr;
    }

    // ---- P A-frags (wave-local read of Ps; lgkmcnt handled by compiler) ----
    int prow = w * 16 + lr, psw = prow & 7;
    s8v pf[4];
#pragma unroll
    for (int jk = 0; jk < 4; jk++)
        pf[jk] = *(const s8v*)((char*)Ps + prow * 256 + ((((jk << 2) | lq) ^ psw) << 4));

    __syncthreads();                              // #4: all waves done with Bs (phase A)

    // ---- Qs0 = stage 0; prefetch stage 1 ----
#pragma unroll
    for (int i = 0; i < 4; i++) {
        int g = tid + (i << 8);
        int dr = g >> 4, cq = g & 15;
        *(u4v*)((char*)Bs + dr * 256 + ((cq ^ (dr & 7)) << 4)) = qreg[i];
    }
#pragma unroll
    for (int i = 0; i < 4; i++) {
        int g = tid + (i << 8);
        int dr = g >> 4, cq = g & 15;
        qreg[i] = *(const u4v*)(qThB + (64 + dr) * J_ + (cq << 3));
    }
    __syncthreads();                              // #5: Qs0 visible

    // ---- phase B: 8 stages of 64 d-rows (hi x4 then lo x4), 1 barrier/stage ----
    f4 acc2[16];
#pragma unroll
    for (int df = 0; df < 16; df++) acc2[df] = (f4){0.f, 0.f, 0.f, 0.f};

#pragma unroll
    for (int s = 0; s < 8; s++) {
        char* qb = (char*)Bs + (s & 1) * 16384;
        int dbase = (s & 3) * 4;
#pragma unroll
        for (int dfl = 0; dfl < 4; dfl++) {
            int dr = dfl * 16 + lr;
            int sw2 = dr & 7;
#pragma unroll
            for (int jk = 0; jk < 4; jk++) {
                s8v bv = *(const s8v*)(qb + dr * 256 + ((((jk << 2) | lq) ^ sw2) << 4));
                acc2[dbase + dfl] = __builtin_amdgcn_mfma_f32_16x16x32_bf16(pf[jk], bv, acc2[dbase + dfl], 0, 0, 0);
            }
        }
        if (s < 7) {
            // write prefetched stage s+1 into the buffer drained at stage s-1
            char* wb = (char*)Bs + ((s + 1) & 1) * 16384;
#pragma unroll
            for (int i = 0; i < 4; i++) {
                int g = tid + (i << 8);
                int dr = g >> 4, cq = g & 15;
                *(u4v*)(wb + dr * 256 + ((cq ^ (dr & 7)) << 4)) = qreg[i];
            }
            if (s < 6) {
                int s2 = s + 2;
                const unsigned short* src = (s2 < 4) ? (qThB + (s2 << 6) * J_)
                                                     : (qTlB + ((s2 - 4) << 6) * J_);
#pragma unroll
                for (int i = 0; i < 4; i++) {
                    int g = tid + (i << 8);
                    int dr = g >> 4, cq = g & 15;
                    qreg[i] = *(const u4v*)(src + dr * J_ + (cq << 3));
                }
            }
            __syncthreads();                      // one barrier per stage
        }
    }

    // ---- epilogue: quarters 2 (c2q) and 3 (ctx*c2q) ----
#pragma unroll
    for (int df = 0; df < 16; df++) {
        int d = df * 16 + lr;
#pragma unroll
        for (int r = 0; r < 4; r++) {
            int t = t0 + rowbase + r;
            int o = b * T_ + t;
            float val = acc2[df][r];
            float cx = ctx[o * D_ + d];
            out[o * 1024 + 256 + d] = val;
            out[o * 1024 + 512 + d] = cx * val;
        }
    }
}

// ---------------- K3: softmax(M) over T; q2c[b,d] = sum_t w_t*ctx[b,t,d] ----------------
__global__ __launch_bounds__(256) void k_q2c(const float* __restrict__ ctx, const float* __restrict__ M,
                                             float* __restrict__ q2c) {
    int b = blockIdx.x >> 4, dc = blockIdx.x & 15;
    int tid = threadIdx.x;
    const float* Mb = M + b * T_;

    float mx = -1e30f;
    for (int i = tid; i < T_; i += 256) mx = fmaxf(mx, Mb[i]);
#pragma unroll
    for (int m = 32; m >= 1; m >>= 1) mx = fmaxf(mx, __shfl_xor(mx, m));
    __shared__ float rA[4], rB[4];
    if ((tid & 63) == 0) rA[tid >> 6] = mx;
    __syncthreads();
    mx = fmaxf(fmaxf(rA[0], rA[1]), fmaxf(rA[2], rA[3]));

    float sm = 0.f;
    for (int i = tid; i < T_; i += 256) sm += __expf(Mb[i] - mx);
#pragma unroll
    for (int m = 32; m >= 1; m >>= 1) sm += __shfl_xor(sm, m);
    if ((tid & 63) == 0) rB[tid >> 6] = sm;
    __syncthreads();
    sm = rB[0] + rB[1] + rB[2] + rB[3];

    int dl = tid & 15, g = tid >> 4;
    int d = dc * 16 + dl;
    float acc = 0.f;
    for (int t = g; t < T_; t += 16)
        acc += __expf(Mb[t] - mx) * ctx[(b * T_ + t) * D_ + d];
    __shared__ float red[16][17];
    red[g][dl] = acc;
    __syncthreads();
    if (g == 0) {
        float s = 0.f;
#pragma unroll
        for (int k2 = 0; k2 < 16; k2++) s += red[k2][dl];
        q2c[b * D_ + d] = s / sm;
    }
}

// ---------------- K4: quarters 1 (ctx) and 4 (ctx*q2c) ----------------
__global__ __launch_bounds__(256) void k_out14(const float* __restrict__ ctx, const float* __restrict__ q2c,
                                               float* __restrict__ out) {
    int idx = blockIdx.x * 256 + threadIdx.x;   // f4 index
    int e = idx * 4;
    int b = e >> 18;            // T*D = 2^18
    int t = (e >> 8) & 1023;
    int d = e & 255;
    f4 cv = *(const f4*)&ctx[e];
    f4 qv = *(const f4*)&q2c[b * D_ + d];
    int ob = (b * T_ + t) * 1024 + d;
    *(f4*)&out[ob] = cv;
    *(f4*)&out[ob + 768] = cv * qv;
}

extern "C" void kernel_launch(void* const* d_in, const int* in_sizes, int n_in,
                              void* d_out, int out_size, void* d_ws, size_t ws_size,
                              hipStream_t stream) {
    const float* ctx   = (const float*)d_in[0];
    const float* query = (const float*)d_in[1];
    const float* w     = (const float*)d_in[2];
    float* out = (float*)d_out;

    unsigned short* Bqh = (unsigned short*)d_ws;        // 2 MB
    unsigned short* qTh = Bqh + B_ * J_ * D_;           // 2 MB
    unsigned short* qTl = qTh + B_ * J_ * D_;           // 2 MB
    float* fws = (float*)(qTl + B_ * J_ * D_);
    float* sq  = fws;                                   // 4096
    float* M   = fws + 4096;                            // 32768
    float* q2c = fws + 4096 + 32768;                    // 8192

    k_prep<<<B_ * J_, 256, 0, stream>>>(query, w, Bqh, sq);
    k_tq<<<B_ * 2 * 4, 256, 0, stream>>>(query, qTh, qTl);
    k_main<<<B_ * (T_ / 64), 256, 0, stream>>>(ctx, Bqh, qTh, qTl, sq, M, out);
    k_q2c<<<B_ * 16, 256, 0, stream>>>(ctx, M, q2c);
    k_out14<<<(B_ * T_ * D_ / 4) / 256, 256, 0, stream>>>(ctx, q2c, out);
}

// Round 6
// 69.713 us; speedup vs baseline: 2.4797x; 1.3145x over previous
//
#include <hip/hip_runtime.h>

typedef float f4 __attribute__((ext_vector_type(4)));
typedef short s8v __attribute__((ext_vector_type(8)));        // 8 bf16
typedef unsigned int u4v __attribute__((ext_vector_type(4))); // 16 B

#define B_ 32
#define T_ 1024
#define J_ 128
#define D_ 256

__device__ inline unsigned short f2bf(float x) {
    unsigned int u = __float_as_uint(x);
    u += 0x7fffu + ((u >> 16) & 1u);      // RNE
    return (unsigned short)(u >> 16);
}
__device__ inline float bf2f(unsigned short h) {
    return __uint_as_float(((unsigned int)h) << 16);
}

// ---------------- K1: Bqh = bf16(w3*q+w1); sq = q.w2 ; zero q2c ----------------
__global__ __launch_bounds__(256) void k_prep(const float* __restrict__ q, const float* __restrict__ w,
                                              unsigned short* __restrict__ Bqh, float* __restrict__ sq,
                                              float* __restrict__ q2c) {
    int bj = blockIdx.x;
    int d = threadIdx.x;
    if (bj < B_) q2c[bj * D_ + d] = 0.f;      // re-zero every call (atomic target)
    float qv = q[bj * D_ + d];
    float w1 = w[d], w2 = w[D_ + d], w3 = w[2 * D_ + d];
    Bqh[bj * D_ + d] = f2bf(w3 * qv + w1);
    float p = qv * w2;
#pragma unroll
    for (int m = 32; m >= 1; m >>= 1) p += __shfl_xor(p, m);
    __shared__ float red[4];
    if ((d & 63) == 0) red[d >> 6] = p;
    __syncthreads();
    if (d == 0) sq[bj] = red[0] + red[1] + red[2] + red[3];
}

// ---------------- K1b: qT_hi/lo[b,d,j] = transpose + hi/lo bf16 split of query ----------------
__global__ __launch_bounds__(256) void k_tq(const float* __restrict__ q,
                                            unsigned short* __restrict__ qTh, unsigned short* __restrict__ qTl) {
    __shared__ float t_[64][65];
    int b = blockIdx.x >> 3, jt = (blockIdx.x >> 2) & 1, dt = blockIdx.x & 3;
    const float* qb = q + (b * J_ + jt * 64) * D_ + dt * 64;
#pragma unroll
    for (int i = 0; i < 16; i++) {
        int lin = threadIdx.x + 256 * i;
        int jj = lin >> 6, dd = lin & 63;
        t_[jj][dd] = qb[jj * D_ + dd];
    }
    __syncthreads();
#pragma unroll
    for (int i = 0; i < 16; i++) {
        int lin = threadIdx.x + 256 * i;
        int dd = lin >> 6, jj = lin & 63;
        float v = t_[jj][dd];
        unsigned short h = f2bf(v);
        unsigned short lo = f2bf(v - bf2f(h));
        int o = (b * D_ + dt * 64 + dd) * J_ + jt * 64 + jj;
        qTh[o] = h;
        qTl[o] = lo;
    }
}

// ---------------- K2: 32-row tile, split-wave MFMA S -> merged softmax -> split MFMA PV -> q1,q2,q3 ----------------
__global__ __launch_bounds__(256, 3) void k_main(const float* __restrict__ ctx,
                                                 const unsigned short* __restrict__ Bqh,
                                                 const unsigned short* __restrict__ qTh,
                                                 const unsigned short* __restrict__ qTl,
                                                 const float* __restrict__ sq,
                                                 float* __restrict__ M, float* __restrict__ out) {
    __shared__ __align__(16) char lds[41472];
    // [0,32768): Bq half (phase A) / 2x16KB qT stages (phase B) / c2q fp32 32x256 (epilogue)
    // [32768,40960): Ps 32x128 bf16 swizzled
    // [40960,41472): softmax scratch sc[32][2][2]
    char* Bs = lds;
    char* Ps = lds + 32768;
    float* sc = (float*)(lds + 40960);

    int b  = blockIdx.x >> 5;
    int t0 = (blockIdx.x & 31) << 5;
    int tid = threadIdx.x;
    int w = tid >> 6, l = tid & 63, lr = l & 15, lq = l >> 4;
    int rg = w & 1, ch = w >> 1;          // phase A: row-group / j-half
    int R0 = rg << 4;

    const unsigned short* BqB  = Bqh + b * J_ * D_;
    const unsigned short* qThB = qTh + b * D_ * J_;
    const unsigned short* qTlB = qTl + b * D_ * J_;

    // ---- prologue: issue loads (h0, ctx first half, h1, ctx second half) ----
    u4v h0[8], h1[8];
#pragma unroll
    for (int i = 0; i < 8; i++) {
        int g = tid + (i << 8);
        int jr = g >> 4, c = g & 15;
        h0[i] = *(const u4v*)(BqB + jr * D_ + c * 8);
    }
    const float* ctxA = ctx + (b * T_ + t0 + R0 + lr) * D_;
    s8v af[8];
#pragma unroll
    for (int k = 0; k < 4; k++) {
        f4 a0 = *(const f4*)(ctxA + k * 32 + lq * 8);
        f4 a1 = *(const f4*)(ctxA + k * 32 + lq * 8 + 4);
        union { unsigned short u[8]; s8v v; } t;
#pragma unroll
        for (int e = 0; e < 4; e++) { t.u[e] = f2bf(a0[e]); t.u[e + 4] = f2bf(a1[e]); }
        af[k] = t.v;
    }
#pragma unroll
    for (int i = 0; i < 8; i++) {
        int g = tid + (i << 8);
        int jr = g >> 4, c = g & 15;
        h1[i] = *(const u4v*)(BqB + jr * D_ + 128 + c * 8);
    }
#pragma unroll
    for (int k = 4; k < 8; k++) {
        f4 a0 = *(const f4*)(ctxA + k * 32 + lq * 8);
        f4 a1 = *(const f4*)(ctxA + k * 32 + lq * 8 + 4);
        union { unsigned short u[8]; s8v v; } t;
#pragma unroll
        for (int e = 0; e < 4; e++) { t.u[e] = f2bf(a0[e]); t.u[e + 4] = f2bf(a1[e]); }
        af[k] = t.v;
    }

    // ---- write Bq half 0 (d 0..127, all j) ----
#pragma unroll
    for (int i = 0; i < 8; i++) {
        int g = tid + (i << 8);
        int jr = g >> 4, c = g & 15;
        *(u4v*)(Bs + jr * 256 + ((c ^ (jr & 7)) << 4)) = h0[i];
    }

    f4 acc[4];
#pragma unroll
    for (int nf = 0; nf < 4; nf++) acc[nf] = (f4){0.f, 0.f, 0.f, 0.f};

    __syncthreads();                          // A1: half0 visible
#pragma unroll
    for (int k2 = 0; k2 < 4; k2++)
#pragma unroll
        for (int nf = 0; nf < 4; nf++) {
            int jr = (ch << 6) + (nf << 4) + lr;
            s8v bv = *(const s8v*)(Bs + jr * 256 + ((((k2 << 2) + lq) ^ (jr & 7)) << 4));
            acc[nf] = __builtin_amdgcn_mfma_f32_16x16x32_bf16(af[k2], bv, acc[nf], 0, 0, 0);
        }
    __syncthreads();                          // A2: half0 drained
#pragma unroll
    for (int i = 0; i < 8; i++) {
        int g = tid + (i << 8);
        int jr = g >> 4, c = g & 15;
        *(u4v*)(Bs + jr * 256 + ((c ^ (jr & 7)) << 4)) = h1[i];
    }
    // prefetch qT stage 0 (hi, d 0..63)
    u4v qreg[4];
#pragma unroll
    for (int i = 0; i < 4; i++) {
        int g = tid + (i << 8);
        int dr = g >> 4, c = g & 15;
        qreg[i] = *(const u4v*)(qThB + dr * J_ + c * 8);
    }
    __syncthreads();                          // A3: half1 visible
#pragma unroll
    for (int k2 = 0; k2 < 4; k2++)
#pragma unroll
        for (int nf = 0; nf < 4; nf++) {
            int jr = (ch << 6) + (nf << 4) + lr;
            s8v bv = *(const s8v*)(Bs + jr * 256 + ((((k2 << 2) + lq) ^ (jr & 7)) << 4));
            acc[nf] = __builtin_amdgcn_mfma_f32_16x16x32_bf16(af[4 + k2], bv, acc[nf], 0, 0, 0);
        }

    // ---- softmax partials over this wave's 64 cols ----
    float sqv[4];
#pragma unroll
    for (int nf = 0; nf < 4; nf++) sqv[nf] = sq[b * J_ + (ch << 6) + (nf << 4) + lr];
    float mp[4], sp[4];
#pragma unroll
    for (int r = 0; r < 4; r++) {
        float m = -1e30f;
#pragma unroll
        for (int nf = 0; nf < 4; nf++) { acc[nf][r] += sqv[nf]; m = fmaxf(m, acc[nf][r]); }
#pragma unroll
        for (int msk = 8; msk >= 1; msk >>= 1) m = fmaxf(m, __shfl_xor(m, msk));
        float s = 0.f;
#pragma unroll
        for (int nf = 0; nf < 4; nf++) { float e = __expf(acc[nf][r] - m); acc[nf][r] = e; s += e; }
#pragma unroll
        for (int msk = 8; msk >= 1; msk >>= 1) s += __shfl_xor(s, msk);
        mp[r] = m; sp[r] = s;
        if (lr == 0) {
            int row = R0 + (lq << 2) + r;
            sc[(row << 2) + (ch << 1)] = m;
            sc[(row << 2) + (ch << 1) + 1] = s;
        }
    }
    __syncthreads();                          // A4: partials visible; Bs drained

    // ---- write qT stage 0; load stage 1 ----
#pragma unroll
    for (int i = 0; i < 4; i++) {
        int g = tid + (i << 8);
        int dr = g >> 4, c = g & 15;
        *(u4v*)(Bs + dr * 256 + ((c ^ (dr & 7)) << 4)) = qreg[i];
    }
#pragma unroll
    for (int i = 0; i < 4; i++) {
        int g = tid + (i << 8);
        int dr = g >> 4, c = g & 15;
        qreg[i] = *(const u4v*)(qThB + (64 + dr) * J_ + c * 8);
    }

    // ---- merge halves, write P (bf16 swizzled) and M ----
#pragma unroll
    for (int r = 0; r < 4; r++) {
        int row = R0 + (lq << 2) + r;
        float m0 = sc[(row << 2)],     s0 = sc[(row << 2) + 1];
        float m1 = sc[(row << 2) + 2], s1 = sc[(row << 2) + 3];
        float m = fmaxf(m0, m1);
        float sum = s0 * __expf(m0 - m) + s1 * __expf(m1 - m);
        float scale = __expf(mp[r] - m) / sum;
#pragma unroll
        for (int nf = 0; nf < 4; nf++) {
            int cc = (ch << 6) + (nf << 4) + lr;
            int chunk = cc >> 3;
            *(unsigned short*)(Ps + row * 256 + ((chunk ^ (row & 7)) << 4) + ((lr & 7) << 1)) =
                f2bf(acc[nf][r] * scale);
        }
        if (ch == 0 && lr == 0) M[b * T_ + t0 + row] = m;
    }
    __syncthreads();                          // A5: Ps + stage0 visible

    // ---- phase B: P(32x128) . q(128x256), 8 stages of 64 d-rows, 1 barrier/stage ----
    int dh2 = w >> 1;                         // d-half within stage
    int prow = R0 + lr;
    s8v pf[4];
#pragma unroll
    for (int jk = 0; jk < 4; jk++)
        pf[jk] = *(const s8v*)(Ps + prow * 256 + ((((jk << 2) + lq) ^ (prow & 7)) << 4));

    f4 acc2[8];
#pragma unroll
    for (int ai = 0; ai < 8; ai++) acc2[ai] = (f4){0.f, 0.f, 0.f, 0.f};

#pragma unroll
    for (int s = 0; s < 8; s++) {
        char* rb = Bs + ((s & 1) << 14);
        if (s < 7) {                          // write stage s+1 into buffer drained at round s-1
            char* wb = Bs + (((s + 1) & 1) << 14);
#pragma unroll
            for (int i = 0; i < 4; i++) {
                int g = tid + (i << 8);
                int dr = g >> 4, c = g & 15;
                *(u4v*)(wb + dr * 256 + ((c ^ (dr & 7)) << 4)) = qreg[i];
            }
        }
        if (s < 6) {                          // issue loads for stage s+2
            const unsigned short* src = (s + 2 < 4) ? (qThB + ((s + 2) << 6) * J_)
                                                    : (qTlB + ((s - 2) << 6) * J_);
#pragma unroll
            for (int i = 0; i < 4; i++) {
                int g = tid + (i << 8);
                int dr = g >> 4, c = g & 15;
                qreg[i] = *(const u4v*)(src + dr * J_ + c * 8);
            }
        }
#pragma unroll
        for (int df2 = 0; df2 < 2; df2++) {
            int dr = (((dh2 << 1) + df2) << 4) + lr;
            int ai = ((s & 3) << 1) + df2;
#pragma unroll
            for (int jk = 0; jk < 4; jk++) {
                s8v bv = *(const s8v*)(rb + dr * 256 + ((((jk << 2) + lq) ^ (dr & 7)) << 4));
                acc2[ai] = __builtin_amdgcn_mfma_f32_16x16x32_bf16(pf[jk], bv, acc2[ai], 0, 0, 0);
            }
        }
        if (s < 7) __syncthreads();
    }
    __syncthreads();                          // B-final: stage bufs drained

    // ---- epilogue: acc2 -> LDS (swizzled) -> f4-coalesced q1,q2,q3 ----
    float* cq = (float*)Bs;
#pragma unroll
    for (int s2 = 0; s2 < 4; s2++)
#pragma unroll
        for (int df2 = 0; df2 < 2; df2++) {
            int col = (s2 << 6) + (dh2 << 5) + (df2 << 4) + lr;
            int ai = (s2 << 1) + df2;
            int chunk = col >> 2;
#pragma unroll
            for (int r = 0; r < 4; r++) {
                int row = R0 + (lq << 2) + r;
                *(float*)((char*)cq + (row << 10) + ((chunk ^ (row & 7)) << 4) + ((col & 3) << 2)) = acc2[ai][r];
            }
        }
    __syncthreads();

    int row = tid >> 3;                       // 0..31
    int o = b * T_ + t0 + row;
    const float* crow = ctx + o * D_;
    float* orow = out + o * 1024;
#pragma unroll
    for (int i = 0; i < 8; i++) {
        int col4 = (i << 5) + ((tid & 7) << 2);
        int chunk = col4 >> 2;
        f4 val = *(const f4*)((char*)cq + (row << 10) + ((chunk ^ (row & 7)) << 4));
        f4 cx = *(const f4*)(crow + col4);
        *(f4*)(orow + col4) = cx;
        *(f4*)(orow + 256 + col4) = val;
        *(f4*)(orow + 512 + col4) = cx * val;
    }
}

// ---------------- K3: softmax(M) weights; coalesced partial q2c via atomics ----------------
__global__ __launch_bounds__(256) void k_q2c(const float* __restrict__ ctx, const float* __restrict__ M,
                                             float* __restrict__ q2c) {
    int b = blockIdx.x >> 5, tc = blockIdx.x & 31;
    int tid = threadIdx.x;
    const float* Mb = M + b * T_;

    float v0 = Mb[tid], v1 = Mb[tid + 256], v2 = Mb[tid + 512], v3 = Mb[tid + 768];
    float mx = fmaxf(fmaxf(v0, v1), fmaxf(v2, v3));
#pragma unroll
    for (int m = 32; m >= 1; m >>= 1) mx = fmaxf(mx, __shfl_xor(mx, m));
    __shared__ float rA[4], rB[4], wt[32];
    if ((tid & 63) == 0) rA[tid >> 6] = mx;
    __syncthreads();
    mx = fmaxf(fmaxf(rA[0], rA[1]), fmaxf(rA[2], rA[3]));

    float sm = __expf(v0 - mx) + __expf(v1 - mx) + __expf(v2 - mx) + __expf(v3 - mx);
#pragma unroll
    for (int m = 32; m >= 1; m >>= 1) sm += __shfl_xor(sm, m);
    if ((tid & 63) == 0) rB[tid >> 6] = sm;
    if (tid < 32) wt[tid] = __expf(Mb[tc * 32 + tid] - mx);
    __syncthreads();
    sm = rB[0] + rB[1] + rB[2] + rB[3];

    float acc = 0.f;
    const float* cb = ctx + (b * T_ + tc * 32) * D_ + tid;
#pragma unroll 8
    for (int tt = 0; tt < 32; tt++) acc += wt[tt] * cb[tt * D_];
    atomicAdd(&q2c[b * D_ + tid], acc / sm);
}

// ---------------- K4: quarter 4 (ctx*q2c) ----------------
__global__ __launch_bounds__(256) void k_out4(const float* __restrict__ ctx, const float* __restrict__ q2c,
                                              float* __restrict__ out) {
    int idx = blockIdx.x * 256 + threadIdx.x;   // f4 index
    int e = idx * 4;
    int b = e >> 18;
    int t = (e >> 8) & 1023;
    int d = e & 255;
    f4 cv = *(const f4*)&ctx[e];
    f4 qv = *(const f4*)&q2c[b * D_ + d];
    *(f4*)&out[(b * T_ + t) * 1024 + 768 + d] = cv * qv;
}

extern "C" void kernel_launch(void* const* d_in, const int* in_sizes, int n_in,
                              void* d_out, int out_size, void* d_ws, size_t ws_size,
                              hipStream_t stream) {
    const float* ctx   = (const float*)d_in[0];
    const float* query = (const float*)d_in[1];
    const float* w     = (const float*)d_in[2];
    float* out = (float*)d_out;

    unsigned short* Bqh = (unsigned short*)d_ws;        // 2 MB
    unsigned short* qTh = Bqh + B_ * J_ * D_;           // 2 MB
    unsigned short* qTl = qTh + B_ * J_ * D_;           // 2 MB
    float* fws = (float*)(qTl + B_ * J_ * D_);
    float* sq  = fws;                                   // 4096
    float* M   = fws + 4096;                            // 32768
    float* q2c = fws + 4096 + 32768;                    // 8192

    k_prep<<<B_ * J_, 256, 0, stream>>>(query, w, Bqh, sq, q2c);
    k_tq<<<B_ * 2 * 4, 256, 0, stream>>>(query, qTh, qTl);
    k_main<<<B_ * (T_ / 32), 256, 0, stream>>>(ctx, Bqh, qTh, qTl, sq, M, out);
    k_q2c<<<B_ * 32, 256, 0, stream>>>(ctx, M, q2c);
    k_out4<<<(B_ * T_ * D_ / 4) / 256, 256, 0, stream>>>(ctx, q2c, out);
}

// Round 7
// 67.294 us; speedup vs baseline: 2.5688x; 1.0359x over previous
//
#include <hip/hip_runtime.h>

typedef float f4 __attribute__((ext_vector_type(4)));
typedef short s8v __attribute__((ext_vector_type(8)));        // 8 bf16

#define B_ 32
#define T_ 1024
#define J_ 128
#define D_ 256

__device__ inline unsigned short f2bf(float x) {
    unsigned int u = __float_as_uint(x);
    u += 0x7fffu + ((u >> 16) & 1u);      // RNE
    return (unsigned short)(u >> 16);
}

__device__ __forceinline__ void ldsload16(const void* g, void* l) {
    __builtin_amdgcn_global_load_lds(
        (const __attribute__((address_space(1))) void*)g,
        (__attribute__((address_space(3))) void*)l, 16, 0, 0);
}

// ---------------- K1: Bqh = bf16(w3*q+w1); sq = q.w2 ; zero q2c ----------------
__global__ __launch_bounds__(256) void k_prep(const float* __restrict__ q, const float* __restrict__ w,
                                              unsigned short* __restrict__ Bqh, float* __restrict__ sq,
                                              float* __restrict__ q2c) {
    int bj = blockIdx.x;
    int d = threadIdx.x;
    if (bj < B_) q2c[bj * D_ + d] = 0.f;      // re-zero every call (atomic target)
    float qv = q[bj * D_ + d];
    float w1 = w[d], w2 = w[D_ + d], w3 = w[2 * D_ + d];
    Bqh[bj * D_ + d] = f2bf(w3 * qv + w1);
    float p = qv * w2;
#pragma unroll
    for (int m = 32; m >= 1; m >>= 1) p += __shfl_xor(p, m);
    __shared__ float red[4];
    if ((d & 63) == 0) red[d >> 6] = p;
    __syncthreads();
    if (d == 0) sq[bj] = red[0] + red[1] + red[2] + red[3];
}

// ---------------- K1b: qTh[b,d,j] = bf16 transpose of query ----------------
__global__ __launch_bounds__(256) void k_tq(const float* __restrict__ q,
                                            unsigned short* __restrict__ qTh) {
    __shared__ float t_[64][65];
    int b = blockIdx.x >> 3, jt = (blockIdx.x >> 2) & 1, dt = blockIdx.x & 3;
    const float* qb = q + (b * J_ + jt * 64) * D_ + dt * 64;
#pragma unroll
    for (int i = 0; i < 16; i++) {
        int lin = threadIdx.x + 256 * i;
        int jj = lin >> 6, dd = lin & 63;
        t_[jj][dd] = qb[jj * D_ + dd];
    }
    __syncthreads();
#pragma unroll
    for (int i = 0; i < 16; i++) {
        int lin = threadIdx.x + 256 * i;
        int dd = lin >> 6, jj = lin & 63;
        qTh[(b * D_ + dt * 64 + dd) * J_ + jt * 64 + jj] = f2bf(t_[jj][dd]);
    }
}

// ---------------- K2: gl_lds-staged MFMA S -> merged softmax -> MFMA PV -> q1,q2,q3 ----------------
__global__ __launch_bounds__(256, 3) void k_main(const float* __restrict__ ctx,
                                                 const unsigned short* __restrict__ Bqh,
                                                 const unsigned short* __restrict__ qTh,
                                                 const float* __restrict__ sq,
                                                 float* __restrict__ M, float* __restrict__ out) {
    __shared__ __align__(16) char lds[41472];
    char* B0 = lds;                // 16 KB buf0 (phase A quarters / phase B stages / epilogue cq lo)
    char* B1 = lds + 16384;        // 16 KB buf1
    char* Ps = lds + 32768;        // 8 KB: P 32x128 bf16, swizzled
    float* sc = (float*)(lds + 40960);  // 512 B softmax scratch

    int b  = blockIdx.x >> 5;
    int t0 = (blockIdx.x & 31) << 5;
    int tid = threadIdx.x;
    int w = tid >> 6, l = tid & 63, lr = l & 15, lq = l >> 4;
    int rg = w & 1, ch = w >> 1;          // phase A: row-group / j-half
    int R0 = rg << 4;

    const unsigned short* BqB  = Bqh + b * J_ * D_;
    const unsigned short* qThB = qTh + b * D_ * J_;

    // stage one 16KB d-quarter of Bq: [128 j][64 d] bf16, linear LDS, source pre-swizzled
    auto stageBq = [&](char* buf, int qt) {
#pragma unroll
        for (int i = 0; i < 4; i++) {
            int g = tid + (i << 8);
            int jr = g >> 3, c = g & 7;
            ldsload16(BqB + jr * D_ + (qt << 6) + ((c ^ (jr & 7)) << 3),
                      buf + (i << 12) + (w << 10));
        }
    };
    // stage one 16KB qT block: [64 d][128 j] bf16
    auto stageQ = [&](char* buf, int st) {
#pragma unroll
        for (int i = 0; i < 4; i++) {
            int g = tid + (i << 8);
            int dr = g >> 4, c = g & 15;
            ldsload16(qThB + ((st << 6) + dr) * J_ + ((c ^ (dr & 7)) << 3),
                      buf + (i << 12) + (w << 10));
        }
    };

    f4 acc[4];
#pragma unroll
    for (int nf = 0; nf < 4; nf++) acc[nf] = (f4){0.f, 0.f, 0.f, 0.f};

    stageBq(B0, 0);
    stageBq(B1, 1);

    // ctx rows -> bf16 A-frags
    const float* ctxA = ctx + (b * T_ + t0 + R0 + lr) * D_;
    s8v af[8];
    {
        f4 c0[8], c1[8];
#pragma unroll
        for (int k = 0; k < 8; k++) {
            c0[k] = *(const f4*)(ctxA + k * 32 + lq * 8);
            c1[k] = *(const f4*)(ctxA + k * 32 + lq * 8 + 4);
        }
#pragma unroll
        for (int k = 0; k < 8; k++) {
            union { unsigned short u[8]; s8v v; } t;
#pragma unroll
            for (int e = 0; e < 4; e++) { t.u[e] = f2bf(c0[k][e]); t.u[e + 4] = f2bf(c1[k][e]); }
            af[k] = t.v;
        }
    }

    auto mfmaA = [&](char* buf, int qt) {
#pragma unroll
        for (int kk = 0; kk < 2; kk++)
#pragma unroll
            for (int nf = 0; nf < 4; nf++) {
                int jr = (ch << 6) + (nf << 4) + lr;
                s8v bv = *(const s8v*)(buf + (jr << 7) + ((((kk << 2) | lq) ^ (jr & 7)) << 4));
                acc[nf] = __builtin_amdgcn_mfma_f32_16x16x32_bf16(af[(qt << 1) | kk], bv, acc[nf], 0, 0, 0);
            }
    };

    __syncthreads();               // S1: q0,q1 staged
    mfmaA(B0, 0);
    __syncthreads();               // S2: B0 free
    stageBq(B0, 2);
    mfmaA(B1, 1);
    __syncthreads();               // S3: q2 staged, B1 free
    stageBq(B1, 3);
    mfmaA(B0, 2);
    __syncthreads();               // S4: q3 staged, B0 free
    stageQ(B0, 0);                 // P-stage0 flies under q3 MFMAs
    mfmaA(B1, 3);

    // ---- softmax partials over this wave's 64 cols ----
    float sqv[4];
#pragma unroll
    for (int nf = 0; nf < 4; nf++) sqv[nf] = sq[b * J_ + (ch << 6) + (nf << 4) + lr];
    float mp[4];
#pragma unroll
    for (int r = 0; r < 4; r++) {
        float m = -1e30f;
#pragma unroll
        for (int nf = 0; nf < 4; nf++) { acc[nf][r] += sqv[nf]; m = fmaxf(m, acc[nf][r]); }
#pragma unroll
        for (int msk = 8; msk >= 1; msk >>= 1) m = fmaxf(m, __shfl_xor(m, msk));
        float s = 0.f;
#pragma unroll
        for (int nf = 0; nf < 4; nf++) { float e = __expf(acc[nf][r] - m); acc[nf][r] = e; s += e; }
#pragma unroll
        for (int msk = 8; msk >= 1; msk >>= 1) s += __shfl_xor(s, msk);
        mp[r] = m;
        if (lr == 0) {
            int row = R0 + (lq << 2) + r;
            sc[(row << 2) + (ch << 1)] = m;
            sc[(row << 2) + (ch << 1) + 1] = s;
        }
    }
    __syncthreads();               // S5: sc visible, B1 free, stage0 staged
    stageQ(B1, 1);                 // stage1 flies under merge

    // ---- merge halves, write P (bf16 swizzled) and M ----
#pragma unroll
    for (int r = 0; r < 4; r++) {
        int row = R0 + (lq << 2) + r;
        float m0 = sc[(row << 2)],     s0 = sc[(row << 2) + 1];
        float m1 = sc[(row << 2) + 2], s1 = sc[(row << 2) + 3];
        float m = fmaxf(m0, m1);
        float sum = s0 * __expf(m0 - m) + s1 * __expf(m1 - m);
        float scale = __expf(mp[r] - m) / sum;
#pragma unroll
        for (int nf = 0; nf < 4; nf++) {
            int cc = (ch << 6) + (nf << 4) + lr;
            int chunk = cc >> 3;
            *(unsigned short*)(Ps + row * 256 + ((chunk ^ (row & 7)) << 4) + ((lr & 7) << 1)) =
                f2bf(acc[nf][r] * scale);
        }
        if (ch == 0 && lr == 0) M[b * T_ + t0 + row] = m;
    }
    __syncthreads();               // S6: Ps visible, stage1 staged

    // ---- phase B: P(32x128) . qT(256x128)^T, 4 stages, bf16-only ----
    int dh2 = w >> 1;
    int prow = R0 + lr;
    s8v pf[4];
#pragma unroll
    for (int jk = 0; jk < 4; jk++)
        pf[jk] = *(const s8v*)(Ps + prow * 256 + ((((jk << 2) + lq) ^ (prow & 7)) << 4));

    f4 acc2[8];
#pragma unroll
    for (int ai = 0; ai < 8; ai++) acc2[ai] = (f4){0.f, 0.f, 0.f, 0.f};

    auto mfmaB = [&](char* rb, int s) {
#pragma unroll
        for (int df2 = 0; df2 < 2; df2++) {
            int dr = (dh2 << 5) + (df2 << 4) + lr;
            int ai = (s << 1) + df2;
#pragma unroll
            for (int jk = 0; jk < 4; jk++) {
                s8v bv = *(const s8v*)(rb + (dr << 8) + ((((jk << 2) + lq) ^ (dr & 7)) << 4));
                acc2[ai] = __builtin_amdgcn_mfma_f32_16x16x32_bf16(pf[jk], bv, acc2[ai], 0, 0, 0);
            }
        }
    };

    mfmaB(B0, 0);
    __syncthreads();               // S7: B0 free
    stageQ(B0, 2);
    mfmaB(B1, 1);
    __syncthreads();               // S8: B1 free, stage2 staged
    stageQ(B1, 3);
    mfmaB(B0, 2);
    __syncthreads();               // S9: stage3 staged
    mfmaB(B1, 3);
    __syncthreads();               // S10: bufs free for epilogue

    // ---- epilogue: acc2 -> LDS (swizzled) -> f4-coalesced nt-stores of q1,q2,q3 ----
    float* cq = (float*)lds;       // 32 rows x 256 cols fp32 = 32 KB
#pragma unroll
    for (int s2 = 0; s2 < 4; s2++)
#pragma unroll
        for (int df2 = 0; df2 < 2; df2++) {
            int col = (s2 << 6) + (dh2 << 5) + (df2 << 4) + lr;
            int ai = (s2 << 1) + df2;
            int chunk = col >> 2;
#pragma unroll
            for (int r = 0; r < 4; r++) {
                int row = R0 + (lq << 2) + r;
                *(float*)((char*)cq + (row << 10) + ((chunk ^ (row & 7)) << 4) + ((col & 3) << 2)) = acc2[ai][r];
            }
        }
    __syncthreads();

    int row = tid >> 3;                       // 0..31
    int o = b * T_ + t0 + row;
    const float* crow = ctx + o * D_;
    float* orow = out + o * 1024;
#pragma unroll
    for (int i = 0; i < 8; i++) {
        int col4 = (i << 5) + ((tid & 7) << 2);
        int chunk = col4 >> 2;
        f4 val = *(const f4*)((char*)cq + (row << 10) + ((chunk ^ (row & 7)) << 4));
        f4 cx = *(const f4*)(crow + col4);
        f4 v3 = cx * val;
        __builtin_nontemporal_store(cx, (f4*)(orow + col4));
        __builtin_nontemporal_store(val, (f4*)(orow + 256 + col4));
        __builtin_nontemporal_store(v3, (f4*)(orow + 512 + col4));
    }
}

// ---------------- K3: softmax(M) weights; coalesced partial q2c via atomics ----------------
__global__ __launch_bounds__(256) void k_q2c(const float* __restrict__ ctx, const float* __restrict__ M,
                                             float* __restrict__ q2c) {
    int b = blockIdx.x >> 5, tc = blockIdx.x & 31;
    int tid = threadIdx.x;
    const float* Mb = M + b * T_;

    float v0 = Mb[tid], v1 = Mb[tid + 256], v2 = Mb[tid + 512], v3 = Mb[tid + 768];
    float mx = fmaxf(fmaxf(v0, v1), fmaxf(v2, v3));
#pragma unroll
    for (int m = 32; m >= 1; m >>= 1) mx = fmaxf(mx, __shfl_xor(mx, m));
    __shared__ float rA[4], rB[4], wt[32];
    if ((tid & 63) == 0) rA[tid >> 6] = mx;
    __syncthreads();
    mx = fmaxf(fmaxf(rA[0], rA[1]), fmaxf(rA[2], rA[3]));

    float sm = __expf(v0 - mx) + __expf(v1 - mx) + __expf(v2 - mx) + __expf(v3 - mx);
#pragma unroll
    for (int m = 32; m >= 1; m >>= 1) sm += __shfl_xor(sm, m);
    if ((tid & 63) == 0) rB[tid >> 6] = sm;
    if (tid < 32) wt[tid] = __expf(Mb[tc * 32 + tid] - mx);
    __syncthreads();
    sm = rB[0] + rB[1] + rB[2] + rB[3];

    float acc = 0.f;
    const float* cb = ctx + (b * T_ + tc * 32) * D_ + tid;
#pragma unroll 8
    for (int tt = 0; tt < 32; tt++) acc += wt[tt] * cb[tt * D_];
    atomicAdd(&q2c[b * D_ + tid], acc / sm);
}

// ---------------- K4: quarter 4 (ctx*q2c) ----------------
__global__ __launch_bounds__(256) void k_out4(const float* __restrict__ ctx, const float* __restrict__ q2c,
                                              float* __restrict__ out) {
    int idx = blockIdx.x * 256 + threadIdx.x;   // f4 index
    int e = idx * 4;
    int b = e >> 18;
    int t = (e >> 8) & 1023;
    int d = e & 255;
    f4 cv = *(const f4*)&ctx[e];
    f4 qv = *(const f4*)&q2c[b * D_ + d];
    f4 r = cv * qv;
    __builtin_nontemporal_store(r, (f4*)&out[(b * T_ + t) * 1024 + 768 + d]);
}

extern "C" void kernel_launch(void* const* d_in, const int* in_sizes, int n_in,
                              void* d_out, int out_size, void* d_ws, size_t ws_size,
                              hipStream_t stream) {
    const float* ctx   = (const float*)d_in[0];
    const float* query = (const float*)d_in[1];
    const float* w     = (const float*)d_in[2];
    float* out = (float*)d_out;

    unsigned short* Bqh = (unsigned short*)d_ws;        // 2 MB
    unsigned short* qTh = Bqh + B_ * J_ * D_;           // 2 MB
    float* fws = (float*)(qTh + B_ * J_ * D_);
    float* sq  = fws;                                   // 4096
    float* M   = fws + 4096;                            // 32768
    float* q2c = fws + 4096 + 32768;                    // 8192

    k_prep<<<B_ * J_, 256, 0, stream>>>(query, w, Bqh, sq, q2c);
    k_tq<<<B_ * 2 * 4, 256, 0, stream>>>(query, qTh);
    k_main<<<B_ * (T_ / 32), 256, 0, stream>>>(ctx, Bqh, qTh, sq, M, out);
    k_q2c<<<B_ * 32, 256, 0, stream>>>(ctx, M, q2c);
    k_out4<<<(B_ * T_ * D_ / 4) / 256, 256, 0, stream>>>(ctx, q2c, out);
}